// Round 6
// baseline (760.858 us; speedup 1.0000x reference)
//
#include <hip/hip_runtime.h>

// GRU fused, round 12: 6+1 wave split.
// Round 11 (602us = 1411 cyc/step): ~2/3 of each step is stall; modeled
// chain = ds_read 120 + MFMA 60 + act ~200 (24 TRANS/lane, quarter rate)
// + write+lgkm+barrier ~150 + FC skew 50. Wall = T x step (blocks all
// concurrent; only 128/256 CUs used) -> shorten the step:
//  - each 16-row tile handled by TWO waves (duplicate the 7 MFMAs, split
//    activations j{0,1}/j{2,3}): act 4->2 sets/lane (24->12 TRANS).
//  - 7th wave does the FC (reads same h buffer, one step behind) ->
//    removes FC skew from the barrier-synced gate waves.
//  - x: 3x float4 per step-PAIR, FIFO 2 bodies deep (4-step slack).
//  - unroll x2: static double-buffer pointers.
// Exchange layout, CSTR=28 banking, fragment mappings identical to the
// validated round-11 kernel.

typedef _Float16 f16x8 __attribute__((ext_vector_type(8)));
typedef float f32x4 __attribute__((ext_vector_type(4)));
typedef __fp16 h2_t __attribute__((ext_vector_type(2)));

namespace {

constexpr int T  = 1024;
constexpr int DM = 6;
constexpr int H  = 48;
constexpr int NB = 16;     // batches per block
constexpr int CSTR = 28;   // dwords per column: 16B-aligned b128 reads,
                           // 2-way max bank aliasing (free per m136)

__device__ __forceinline__ float fexp2(float x) { return __builtin_amdgcn_exp2f(x); }
__device__ __forceinline__ float frcp(float x) { return __builtin_amdgcn_rcpf(x); }
__device__ __forceinline__ float sigmoid_f(float x) {
  return frcp(1.0f + fexp2(-1.44269504088896340736f * x));
}
__device__ __forceinline__ float tanh_f(float x) {
  float e = fexp2(2.88539008177792681472f * x);
  return 1.0f - 2.0f * frcp(e + 1.0f);
}
__device__ __forceinline__ unsigned pk(float a, float b) {   // RTZ (weights/x)
  union { h2_t h; unsigned u; } r; r.h = __builtin_amdgcn_cvt_pkrtz(a, b); return r.u;
}
__device__ __forceinline__ unsigned pk_rtn(float a, float b) {  // RTN (h state)
  union { __fp16 h[2]; unsigned u; } r; r.h[0] = (__fp16)a; r.h[1] = (__fp16)b; return r.u;
}

union F8 { unsigned u[4]; f16x8 v; };

// fused K-column: kk<48 -> W_hh row; 48..53 -> W_ih row (x slots); 54 -> bias.
__device__ __forceinline__ float kv48(const float* Wrow, const float* IHrow,
                                      float bias, int kk) {
  if (kk < 48) return Wrow ? Wrow[kk] : 0.0f;
  if (kk < 54) return IHrow ? IHrow[kk - 48] : 0.0f;
  if (kk == 54) return bias;
  return 0.0f;
}

// Barrier draining LDS only: global x loads (vmcnt) stay in flight.
__device__ __forceinline__ void bar_lgkm() {
  asm volatile("s_waitcnt lgkmcnt(0)\n\ts_barrier" ::: "memory");
}

__global__ __launch_bounds__(448)
void gru_mfma7(
    const float* __restrict__ x, const float* __restrict__ W_ih,
    const float* __restrict__ W_hh, const float* __restrict__ b_ih,
    const float* __restrict__ b_hh, const float* __restrict__ fc_w,
    const float* __restrict__ fc_b, float* __restrict__ y) {

  // [buf][col*CSTR + pair]; pair p of col c = h rows (2p,2p+1), even row low.
  __shared__ unsigned hbuf[2][16 * CSTR];

  const int tid = threadIdx.x;
  const int wid = tid >> 6;
  const int l   = tid & 63;
  const int c   = l & 15;          // batch col (B/C/D) and M-row (A)
  const int q   = l >> 4;          // lane quad
  const size_t bb = (size_t)blockIdx.x * NB;

  const bool isFC = (wid == 6);
  const int tt = isFC ? 0 : (wid >> 1);   // row tile 0..2
  const int jh = isFC ? 0 : (wid & 1);    // j-half: acts on j = 2jh, 2jh+1

  // ---- loop-invariant A fragments ----
  // Gate waves: aR0..aGI for tile tt. FC wave: FC frags live in aR0/aR1.
  F8 aR0, aR1, aZ0, aZ1, aG0, aG1, aGI;
  if (!isFC) {
    const int rrow = tt * 16 + c;
    const int zrow = 48 + tt * 16 + c;
    const int nrow = 96 + tt * 16 + c;
    const float* wr = W_hh + rrow * H; const float* ir  = W_ih + rrow * DM;
    const float* wz = W_hh + zrow * H; const float* iz  = W_ih + zrow * DM;
    const float* wn = W_hh + nrow * H; const float* in_ = W_ih + nrow * DM;
    const float bs = b_ih[rrow] + b_hh[rrow];
    const float bz = b_ih[zrow] + b_hh[zrow];
    const float bh = b_hh[nrow], bi = b_ih[nrow];
#pragma unroll
    for (int w = 0; w < 4; ++w) {
      const int k0 = 8 * q + 2 * w;
      aR0.u[w] = pk(wr[k0], wr[k0 + 1]);
      aZ0.u[w] = pk(wz[k0], wz[k0 + 1]);
      aG0.u[w] = pk(wn[k0], wn[k0 + 1]);
      aR1.u[w] = pk(kv48(wr, ir, bs, 32 + k0), kv48(wr, ir, bs, 33 + k0));
      aZ1.u[w] = pk(kv48(wz, iz, bz, 32 + k0), kv48(wz, iz, bz, 33 + k0));
      aG1.u[w] = pk(kv48(wn, nullptr, bh, 32 + k0), kv48(wn, nullptr, bh, 33 + k0));
      const int kk0 = 2 * w;
      auto gv = [&](int k) -> float { return k < 6 ? in_[k] : (k == 6 ? bi : 0.0f); };
      aGI.u[w] = (q == 0) ? pk(gv(kk0), gv(kk0 + 1)) : 0u;
    }
  } else {
    const bool vr = (c < DM);
    const float* wr = vr ? (fc_w + c * H) : nullptr;
    const float fb = vr ? fc_b[c] : 0.0f;
#pragma unroll
    for (int w = 0; w < 4; ++w) {
      const int k0 = 8 * q + 2 * w;
      aR0.u[w] = wr ? pk(wr[k0], wr[k0 + 1]) : 0u;
      aR1.u[w] = pk(kv48(wr, nullptr, fb, 32 + k0), kv48(wr, nullptr, fb, 33 + k0));
      aZ0.u[w] = 0u; aZ1.u[w] = 0u; aG0.u[w] = 0u; aG1.u[w] = 0u; aGI.u[w] = 0u;
    }
  }

  // zero both h buffers (h[-1] = 0)
  for (int i = tid; i < 2 * 16 * CSTR; i += 448) ((unsigned*)hbuf)[i] = 0u;

  const float* xp = x + (bb + c) * (size_t)(T * DM);
  float* yp = y + (bb + c) * (size_t)(T * DM);
  const bool xl = !isFC && ((q == 0) || (q == 2));

  // x pipeline: 3 float4 per step-pair (pair base is even t -> 16B aligned).
  float4 L0 = {0, 0, 0, 0}, L1 = L0, L2 = L0;
  if (xl) { const float4* p = (const float4*)xp; L0 = p[0]; L1 = p[1]; L2 = p[2]; }
  unsigned xA0 = pk(L0.x, L0.y), xA1 = pk(L0.z, L0.w), xA2 = pk(L1.x, L1.y);
  unsigned xB0 = pk(L1.z, L1.w), xB1 = pk(L2.x, L2.y), xB2 = pk(L2.z, L2.w);
  if (xl) { const float4* p = (const float4*)(xp + 2 * DM); L0 = p[0]; L1 = p[1]; L2 = p[2]; }

  const int rd0 = c * CSTR + 4 * q;           // chunk0: pairs 4q..4q+3
  const int rd1 = c * CSTR + 16 + 4 * q;      // chunk1 (q<2)
  const int wr1 = c * CSTR + 8 * tt + 2 * q + jh;   // this wave's h pair
  const unsigned c10 = 0x00003C00u;           // f16 (1.0, 0.0)
  const f32x4 z4 = {0.0f, 0.0f, 0.0f, 0.0f};
  float hfa = 0.0f, hfb = 0.0f;               // h rows 16tt+4q+2jh+{0,1}, col c

  __syncthreads();

  auto STEP = [&](const unsigned* hb, unsigned* hn,
                  unsigned xw0, unsigned xw1, unsigned xw2, int t) {
    F8 B0, B1, XB;
    const uint4 h0 = *(const uint4*)&hb[rd0];
    uint4 h1 = {0, 0, 0, 0};
    if (q < 2) h1 = *(const uint4*)&hb[rd1];
    B0.u[0] = h0.x; B0.u[1] = h0.y; B0.u[2] = h0.z; B0.u[3] = h0.w;
    const bool q0 = (q == 0), q2 = (q == 2), q3 = (q == 3);
    B1.u[0] = q2 ? (isFC ? 0u : xw0) : (q3 ? 0u : h1.x);
    B1.u[1] = q2 ? (isFC ? 0u : xw1) : (q3 ? 0u : h1.y);
    B1.u[2] = q2 ? (isFC ? 0u : xw2) : (q3 ? 0u : h1.z);
    B1.u[3] = q2 ? c10 : (q3 ? 0u : h1.w);
    XB.u[0] = q0 ? xw0 : 0u; XB.u[1] = q0 ? xw1 : 0u;
    XB.u[2] = q0 ? xw2 : 0u; XB.u[3] = q0 ? c10 : 0u;

    if (isFC) {
      // y[t-1] from h[t-1] (this buffer); gate waves write the OTHER buffer.
      f32x4 ya = __builtin_amdgcn_mfma_f32_16x16x32_f16(aR0.v, B0.v, z4, 0, 0, 0);
      ya = __builtin_amdgcn_mfma_f32_16x16x32_f16(aR1.v, B1.v, ya, 0, 0, 0);
      if (t > 0) {
        if (q0) {
          float2 s0 = {ya[0], ya[1]}, s1 = {ya[2], ya[3]};
          *(float2*)(yp + (t - 1) * DM) = s0;
          *(float2*)(yp + (t - 1) * DM + 2) = s1;
        } else if (q == 1) {
          float2 s = {ya[0], ya[1]};
          *(float2*)(yp + (t - 1) * DM + 4) = s;
        }
      }
    } else {
      f32x4 aR = __builtin_amdgcn_mfma_f32_16x16x32_f16(aR0.v, B0.v, z4, 0, 0, 0);
      aR = __builtin_amdgcn_mfma_f32_16x16x32_f16(aR1.v, B1.v, aR, 0, 0, 0);
      f32x4 aZ = __builtin_amdgcn_mfma_f32_16x16x32_f16(aZ0.v, B0.v, z4, 0, 0, 0);
      aZ = __builtin_amdgcn_mfma_f32_16x16x32_f16(aZ1.v, B1.v, aZ, 0, 0, 0);
      f32x4 aG = __builtin_amdgcn_mfma_f32_16x16x32_f16(aG0.v, B0.v, z4, 0, 0, 0);
      aG = __builtin_amdgcn_mfma_f32_16x16x32_f16(aG1.v, B1.v, aG, 0, 0, 0);
      f32x4 aI = __builtin_amdgcn_mfma_f32_16x16x32_f16(aGI.v, XB.v, z4, 0, 0, 0);

      // j-half select (constant extracts + cndmask; no dynamic vec index)
      const float vr0 = jh ? aR[2] : aR[0], vr1 = jh ? aR[3] : aR[1];
      const float vz0 = jh ? aZ[2] : aZ[0], vz1 = jh ? aZ[3] : aZ[1];
      const float vg0 = jh ? aG[2] : aG[0], vg1 = jh ? aG[3] : aG[1];
      const float vi0 = jh ? aI[2] : aI[0], vi1 = jh ? aI[3] : aI[1];

      const float r0 = sigmoid_f(vr0), zz0 = sigmoid_f(vz0);
      const float n0 = tanh_f(fmaf(r0, vg0, vi0));
      hfa = fmaf(zz0, hfa - n0, n0);
      const float r1 = sigmoid_f(vr1), zz1 = sigmoid_f(vz1);
      const float n1 = tanh_f(fmaf(r1, vg1, vi1));
      hfb = fmaf(zz1, hfb - n1, n1);

      hn[wr1] = pk_rtn(hfa, hfb);               // ds_write_b32
    }
    bar_lgkm();
  };

#pragma unroll 1
  for (int t2 = 0; t2 < T; t2 += 2) {
    STEP(&hbuf[0][0], &hbuf[1][0], xA0, xA1, xA2, t2);
    STEP(&hbuf[1][0], &hbuf[0][0], xB0, xB1, xB2, t2 + 1);
    // commit pair (t2+2) from L*, issue loads for pair (t2+4)
    xA0 = pk(L0.x, L0.y); xA1 = pk(L0.z, L0.w); xA2 = pk(L1.x, L1.y);
    xB0 = pk(L1.z, L1.w); xB1 = pk(L2.x, L2.y); xB2 = pk(L2.z, L2.w);
    if (xl) {
      int pb = t2 + 4; if (pb > T - 2) pb = T - 2;
      const float4* p = (const float4*)(xp + pb * DM);
      L0 = p[0]; L1 = p[1]; L2 = p[2];
    }
  }

  // ---- epilogue: y[T-1] from h[T-1] (last write went to hbuf[0]) ----
  if (isFC) {
    const unsigned* hb = &hbuf[0][0];
    F8 B0, B1;
    const uint4 h0 = *(const uint4*)&hb[rd0];
    B0.u[0] = h0.x; B0.u[1] = h0.y; B0.u[2] = h0.z; B0.u[3] = h0.w;
    uint4 h1 = {0, 0, 0, 0};
    if (q < 2) h1 = *(const uint4*)&hb[rd1];
    const bool q2 = (q == 2), q3 = (q == 3);
    B1.u[0] = (q2 || q3) ? 0u : h1.x;
    B1.u[1] = (q2 || q3) ? 0u : h1.y;
    B1.u[2] = (q2 || q3) ? 0u : h1.z;
    B1.u[3] = q2 ? c10 : (q3 ? 0u : h1.w);
    f32x4 ya = __builtin_amdgcn_mfma_f32_16x16x32_f16(aR0.v, B0.v, z4, 0, 0, 0);
    ya = __builtin_amdgcn_mfma_f32_16x16x32_f16(aR1.v, B1.v, ya, 0, 0, 0);
    if (q == 0) {
      float2 s0 = {ya[0], ya[1]}, s1 = {ya[2], ya[3]};
      *(float2*)(yp + (T - 1) * DM) = s0;
      *(float2*)(yp + (T - 1) * DM + 2) = s1;
    } else if (q == 1) {
      float2 s = {ya[0], ya[1]};
      *(float2*)(yp + (T - 1) * DM + 4) = s;
    }
  }
}

}  // namespace

extern "C" void kernel_launch(void* const* d_in, const int* in_sizes, int n_in,
                              void* d_out, int out_size, void* d_ws, size_t ws_size,
                              hipStream_t stream) {
  const float* x    = (const float*)d_in[0];
  const float* W_ih = (const float*)d_in[1];
  const float* W_hh = (const float*)d_in[2];
  const float* b_ih = (const float*)d_in[3];
  const float* b_hh = (const float*)d_in[4];
  const float* fc_w = (const float*)d_in[5];
  const float* fc_b = (const float*)d_in[6];
  float* y = (float*)d_out;

  constexpr int B = 2048;
  gru_mfma7<<<B / NB, 448, 0, stream>>>(x, W_ih, W_hh, b_ih, b_hh, fc_w, fc_b, y);
}

// Round 8
// 435.134 us; speedup vs baseline: 1.7486x; 1.7486x over previous
//
#include <hip/hip_runtime.h>

// GRU fused, round 14: r13 + init-race fix.
// r13 failed correctness (absmax 0.855): the (1.0,0) bias pair and x[0]
// stores into hbuf raced the multi-wave zero loop (no barrier between).
// Fix: __syncthreads() after zeroing, before payload stores. Design
// otherwise identical to r13:
//  - 3 gate waves (16-row tiles) + service wave (x staging + FC).
//  - x and 1.0 live in the h LDS columns (pairs 24-27, CSTR=36):
//    B1/XB are raw ds_read_b128, no select chain.
//  - sigmoid/tanh argument scales folded into the f16 weight pack.
// Fragment k-mappings identical to the validated r10/r11 kernels.

typedef _Float16 f16x8 __attribute__((ext_vector_type(8)));
typedef float f32x4 __attribute__((ext_vector_type(4)));
typedef __fp16 h2_t __attribute__((ext_vector_type(2)));

namespace {

constexpr int T  = 1024;
constexpr int DM = 6;
constexpr int H  = 48;
constexpr int NB = 16;     // batches per block
constexpr int CSTR = 36;   // dwords per column: pairs 0-23 h, 24-26 x,
                           // 27 (1,0), 28-31 zeros, 32-35 pad.

constexpr float SRZ = -1.44269504088896340736f;  // -log2(e): sigmoid arg
constexpr float SN  =  2.88539008177792681472f;  // 2*log2(e): tanh arg

__device__ __forceinline__ float fexp2(float x) { return __builtin_amdgcn_exp2f(x); }
__device__ __forceinline__ float frcp(float x) { return __builtin_amdgcn_rcpf(x); }
__device__ __forceinline__ unsigned pk(float a, float b) {   // RTZ (weights/x)
  union { h2_t h; unsigned u; } r; r.h = __builtin_amdgcn_cvt_pkrtz(a, b); return r.u;
}
__device__ __forceinline__ unsigned pk_rtn(float a, float b) {  // RTN (h state)
  union { __fp16 h[2]; unsigned u; } r; r.h[0] = (__fp16)a; r.h[1] = (__fp16)b; return r.u;
}

union F8 { unsigned u[4]; f16x8 v; };

// fused K-column: kk<48 -> W_hh row; 48..53 -> W_ih row (x slots); 54 -> bias.
__device__ __forceinline__ float kv48(const float* Wrow, const float* IHrow,
                                      float bias, int kk) {
  if (kk < 48) return Wrow ? Wrow[kk] : 0.0f;
  if (kk < 54) return IHrow ? IHrow[kk - 48] : 0.0f;
  if (kk == 54) return bias;
  return 0.0f;
}

// Barrier draining LDS only: global loads/stores stay in flight.
__device__ __forceinline__ void bar_lgkm() {
  asm volatile("s_waitcnt lgkmcnt(0)\n\ts_barrier" ::: "memory");
}

__global__ __launch_bounds__(256)
void gru_mfma4(
    const float* __restrict__ x, const float* __restrict__ W_ih,
    const float* __restrict__ W_hh, const float* __restrict__ b_ih,
    const float* __restrict__ b_hh, const float* __restrict__ fc_w,
    const float* __restrict__ fc_b, float* __restrict__ y) {

  // [buf][col*CSTR + pair]; pair p of col c = rows (2p,2p+1), even row low.
  __shared__ __align__(16) unsigned hbuf[2][16 * CSTR];

  const int tid = threadIdx.x;
  const int wid = tid >> 6;        // 0..2 gate tiles, 3 = service (x + FC)
  const int l   = tid & 63;
  const int c   = l & 15;          // batch col (B/C/D) and M-row (A)
  const int q   = l >> 4;          // lane quad
  const size_t bb = (size_t)blockIdx.x * NB;
  const bool isSvc = (wid == 3);

  // ---- loop-invariant A fragments ----
  F8 aR0, aR1, aZ0, aZ1, aG0, aG1, aGI;   // gate waves
  F8 aFC0, aFC1;                          // service wave
  if (!isSvc) {
    const int rrow = wid * 16 + c;
    const int zrow = 48 + wid * 16 + c;
    const int nrow = 96 + wid * 16 + c;
    const float* wr = W_hh + rrow * H; const float* ir  = W_ih + rrow * DM;
    const float* wz = W_hh + zrow * H; const float* iz  = W_ih + zrow * DM;
    const float* wn = W_hh + nrow * H; const float* in_ = W_ih + nrow * DM;
    const float bs = b_ih[rrow] + b_hh[rrow];
    const float bz = b_ih[zrow] + b_hh[zrow];
    const float bh = b_hh[nrow], bi = b_ih[nrow];
#pragma unroll
    for (int w = 0; w < 4; ++w) {
      const int k0 = 8 * q + 2 * w;
      aR0.u[w] = pk(SRZ * wr[k0], SRZ * wr[k0 + 1]);
      aZ0.u[w] = pk(SRZ * wz[k0], SRZ * wz[k0 + 1]);
      aG0.u[w] = pk(SN * wn[k0], SN * wn[k0 + 1]);
      aR1.u[w] = pk(SRZ * kv48(wr, ir, bs, 32 + k0), SRZ * kv48(wr, ir, bs, 33 + k0));
      aZ1.u[w] = pk(SRZ * kv48(wz, iz, bz, 32 + k0), SRZ * kv48(wz, iz, bz, 33 + k0));
      aG1.u[w] = pk(SN * kv48(wn, nullptr, bh, 32 + k0), SN * kv48(wn, nullptr, bh, 33 + k0));
      const int kk0 = 2 * w;
      auto gv = [&](int k) -> float { return k < 6 ? in_[k] : (k == 6 ? bi : 0.0f); };
      aGI.u[w] = (q == 0) ? pk(SN * gv(kk0), SN * gv(kk0 + 1)) : 0u;
    }
  } else {
    const bool vr = (c < DM);
    const float* wr = vr ? (fc_w + c * H) : nullptr;
    const float fb = vr ? fc_b[c] : 0.0f;
#pragma unroll
    for (int w = 0; w < 4; ++w) {
      const int k0 = 8 * q + 2 * w;
      aFC0.u[w] = wr ? pk(wr[k0], wr[k0 + 1]) : 0u;
      aFC1.u[w] = pk(kv48(wr, nullptr, fb, 32 + k0), kv48(wr, nullptr, fb, 33 + k0));
    }
  }

  // ---- LDS init: zero everything, BARRIER, then payload stores ----
  for (int i = tid; i < 2 * 16 * CSTR; i += 256) ((unsigned*)hbuf)[i] = 0u;
  __syncthreads();   // r13 bug: payload stores raced the zero loop

  if (tid < 32) hbuf[tid >> 4][(tid & 15) * CSTR + 27] = 0x00003C00u;  // (1.0, 0)

  // service wave x-pipeline: lane ll<48 owns col=ll/3, dword dw=ll%3
  const int ll = (l < 48) ? l : 47;
  const int xcol = ll / 3, xdw = ll - 3 * xcol;
  const float* xptr = x + (bb + xcol) * (size_t)(T * DM) + 2 * xdw;
  const int xwr = xcol * CSTR + 24 + xdw;
  float2 nxt = {0.0f, 0.0f};
  if (isSvc) {
    const float2 v0 = *(const float2*)xptr;                  // x[0]
    if (l < 48) hbuf[0][xwr] = pk(v0.x, v0.y);
    nxt = *(const float2*)(xptr + DM);                       // x[1]
  }

  float* yp = y + (bb + c) * (size_t)(T * DM);
  const f32x4 z4 = {0.0f, 0.0f, 0.0f, 0.0f};
  float hf[4] = {0.0f, 0.0f, 0.0f, 0.0f};  // rows 16wid+4q+j, col c

  const int rd0 = c * CSTR + 4 * q;        // B0: pairs 4q..4q+3  (k 8q..8q+7)
  const int rd1 = c * CSTR + 16 + 4 * q;   // B1: h32-47 | x | (1,0) | zeros
  const int rdx = c * CSTR + 24;           // XB: x | (1,0) (k0..7; aGI zeros rest)
  const int wr_ = c * CSTR + 8 * wid + 2 * q;

  __syncthreads();

  auto STEP = [&](const unsigned* hb, unsigned* hn, int s) {
    if (!isSvc) {
      F8 B0, B1, XB;
      const uint4 h0 = *(const uint4*)&hb[rd0];
      const uint4 h1 = *(const uint4*)&hb[rd1];
      const uint4 xq = *(const uint4*)&hb[rdx];
      B0.u[0] = h0.x; B0.u[1] = h0.y; B0.u[2] = h0.z; B0.u[3] = h0.w;
      B1.u[0] = h1.x; B1.u[1] = h1.y; B1.u[2] = h1.z; B1.u[3] = h1.w;
      XB.u[0] = xq.x; XB.u[1] = xq.y; XB.u[2] = xq.z; XB.u[3] = xq.w;

      f32x4 aR = __builtin_amdgcn_mfma_f32_16x16x32_f16(aR0.v, B0.v, z4, 0, 0, 0);
      aR = __builtin_amdgcn_mfma_f32_16x16x32_f16(aR1.v, B1.v, aR, 0, 0, 0);
      f32x4 aZ = __builtin_amdgcn_mfma_f32_16x16x32_f16(aZ0.v, B0.v, z4, 0, 0, 0);
      aZ = __builtin_amdgcn_mfma_f32_16x16x32_f16(aZ1.v, B1.v, aZ, 0, 0, 0);
      f32x4 aG = __builtin_amdgcn_mfma_f32_16x16x32_f16(aG0.v, B0.v, z4, 0, 0, 0);
      aG = __builtin_amdgcn_mfma_f32_16x16x32_f16(aG1.v, B1.v, aG, 0, 0, 0);
      f32x4 aI = __builtin_amdgcn_mfma_f32_16x16x32_f16(aGI.v, XB.v, z4, 0, 0, 0);

#pragma unroll
      for (int j = 0; j < 4; ++j) {
        const float r_ = frcp(1.0f + fexp2(aR[j]));          // arg pre-scaled
        const float z_ = frcp(1.0f + fexp2(aZ[j]));
        const float u_ = frcp(fexp2(fmaf(r_, aG[j], aI[j])) + 1.0f);
        const float n_ = fmaf(-2.0f, u_, 1.0f);              // tanh
        hf[j] = fmaf(z_, hf[j] - n_, n_);                    // n + z*(h-n)
      }
      hn[wr_]     = pk_rtn(hf[0], hf[1]);
      hn[wr_ + 1] = pk_rtn(hf[2], hf[3]);
    } else {
      // FC: y[s-1] from h[s-1] (this read buffer)
      F8 B0, B1;
      const uint4 h0 = *(const uint4*)&hb[rd0];
      const uint4 h1 = *(const uint4*)&hb[rd1];
      B0.u[0] = h0.x; B0.u[1] = h0.y; B0.u[2] = h0.z; B0.u[3] = h0.w;
      B1.u[0] = h1.x; B1.u[1] = h1.y; B1.u[2] = h1.z; B1.u[3] = h1.w;
      f32x4 ya = __builtin_amdgcn_mfma_f32_16x16x32_f16(aFC0.v, B0.v, z4, 0, 0, 0);
      ya = __builtin_amdgcn_mfma_f32_16x16x32_f16(aFC1.v, B1.v, ya, 0, 0, 0);
      if (s > 0) {
        if (q == 0) {
          float2 s0 = {ya[0], ya[1]}, s1 = {ya[2], ya[3]};
          *(float2*)(yp + (s - 1) * DM) = s0;
          *(float2*)(yp + (s - 1) * DM + 2) = s1;
        } else if (q == 1) {
          float2 sv = {ya[0], ya[1]};
          *(float2*)(yp + (s - 1) * DM + 4) = sv;
        }
      }
      // commit x[s+1] into the write buffer (read next step), issue x[s+2]
      if (l < 48) hn[xwr] = pk(nxt.x, nxt.y);
      const int tn = (s + 2 < T) ? (s + 2) : (T - 1);
      nxt = *(const float2*)(xptr + tn * DM);
    }
    bar_lgkm();
  };

#pragma unroll 1
  for (int s2 = 0; s2 < T; s2 += 2) {
    STEP(&hbuf[0][0], &hbuf[1][0], s2);
    STEP(&hbuf[1][0], &hbuf[0][0], s2 + 1);
  }

  // epilogue: y[T-1] from h[T-1] (in hbuf[0]; last barrier already passed)
  if (isSvc) {
    const unsigned* hb = &hbuf[0][0];
    F8 B0, B1;
    const uint4 h0 = *(const uint4*)&hb[rd0];
    const uint4 h1 = *(const uint4*)&hb[rd1];
    B0.u[0] = h0.x; B0.u[1] = h0.y; B0.u[2] = h0.z; B0.u[3] = h0.w;
    B1.u[0] = h1.x; B1.u[1] = h1.y; B1.u[2] = h1.z; B1.u[3] = h1.w;
    f32x4 ya = __builtin_amdgcn_mfma_f32_16x16x32_f16(aFC0.v, B0.v, z4, 0, 0, 0);
    ya = __builtin_amdgcn_mfma_f32_16x16x32_f16(aFC1.v, B1.v, ya, 0, 0, 0);
    if (q == 0) {
      float2 s0 = {ya[0], ya[1]}, s1 = {ya[2], ya[3]};
      *(float2*)(yp + (T - 1) * DM) = s0;
      *(float2*)(yp + (T - 1) * DM + 2) = s1;
    } else if (q == 1) {
      float2 sv = {ya[0], ya[1]};
      *(float2*)(yp + (T - 1) * DM + 4) = sv;
    }
  }
}

}  // namespace

extern "C" void kernel_launch(void* const* d_in, const int* in_sizes, int n_in,
                              void* d_out, int out_size, void* d_ws, size_t ws_size,
                              hipStream_t stream) {
  const float* x    = (const float*)d_in[0];
  const float* W_ih = (const float*)d_in[1];
  const float* W_hh = (const float*)d_in[2];
  const float* b_ih = (const float*)d_in[3];
  const float* b_hh = (const float*)d_in[4];
  const float* fc_w = (const float*)d_in[5];
  const float* fc_b = (const float*)d_in[6];
  float* y = (float*)d_out;

  constexpr int B = 2048;
  gru_mfma4<<<B / NB, 256, 0, stream>>>(x, W_ih, W_hh, b_ih, b_hh, fc_w, fc_b, y);
}

// Round 9
// 433.662 us; speedup vs baseline: 1.7545x; 1.0034x over previous
//
#include <hip/hip_runtime.h>

// GRU fused, round 15: r14 + chain shavings.
// r14 (356us = 835 cyc/step, validated): act TRANS issue (24x8=192) is the
// largest term, then LDS exchange latency. This round shortens the per-step
// chain without touching the 3-gate+service structure:
//  1. XB ds_read eliminated: n-gate gi rides B1 (aGI A-slots moved to
//     chunk-1 k48-54, q=2 lanes; B1 already holds x + 1.0 there).
//  2. r/z rcp merged: one rcp for both sigmoids via common denominator
//     (24 -> 20 TRANS/step). Safe: |preact| ~14 << 89 overflow bound.
//  3. h pair-0 written to LDS right after j=0,1 (overlaps j=2,3 TRANS).
// Fragment k-mappings identical to validated r10/r11/r14 kernels.

typedef _Float16 f16x8 __attribute__((ext_vector_type(8)));
typedef float f32x4 __attribute__((ext_vector_type(4)));
typedef __fp16 h2_t __attribute__((ext_vector_type(2)));

namespace {

constexpr int T  = 1024;
constexpr int DM = 6;
constexpr int H  = 48;
constexpr int NB = 16;     // batches per block
constexpr int CSTR = 36;   // dwords per column: pairs 0-23 h, 24-26 x,
                           // 27 (1,0), 28-31 zeros, 32-35 pad.

constexpr float SRZ = -1.44269504088896340736f;  // -log2(e): sigmoid arg
constexpr float SN  =  2.88539008177792681472f;  // 2*log2(e): tanh arg

__device__ __forceinline__ float fexp2(float x) { return __builtin_amdgcn_exp2f(x); }
__device__ __forceinline__ float frcp(float x) { return __builtin_amdgcn_rcpf(x); }
__device__ __forceinline__ unsigned pk(float a, float b) {   // RTZ (weights/x)
  union { h2_t h; unsigned u; } r; r.h = __builtin_amdgcn_cvt_pkrtz(a, b); return r.u;
}
__device__ __forceinline__ unsigned pk_rtn(float a, float b) {  // RTN (h state)
  union { __fp16 h[2]; unsigned u; } r; r.h[0] = (__fp16)a; r.h[1] = (__fp16)b; return r.u;
}

union F8 { unsigned u[4]; f16x8 v; };

// fused K-column: kk<48 -> W_hh row; 48..53 -> W_ih row (x slots); 54 -> bias.
__device__ __forceinline__ float kv48(const float* Wrow, const float* IHrow,
                                      float bias, int kk) {
  if (kk < 48) return Wrow ? Wrow[kk] : 0.0f;
  if (kk < 54) return IHrow ? IHrow[kk - 48] : 0.0f;
  if (kk == 54) return bias;
  return 0.0f;
}

// Barrier draining LDS only: global loads/stores stay in flight.
__device__ __forceinline__ void bar_lgkm() {
  asm volatile("s_waitcnt lgkmcnt(0)\n\ts_barrier" ::: "memory");
}

__global__ __launch_bounds__(256)
void gru_mfma5(
    const float* __restrict__ x, const float* __restrict__ W_ih,
    const float* __restrict__ W_hh, const float* __restrict__ b_ih,
    const float* __restrict__ b_hh, const float* __restrict__ fc_w,
    const float* __restrict__ fc_b, float* __restrict__ y) {

  // [buf][col*CSTR + pair]; pair p of col c = rows (2p,2p+1), even row low.
  __shared__ __align__(16) unsigned hbuf[2][16 * CSTR];

  const int tid = threadIdx.x;
  const int wid = tid >> 6;        // 0..2 gate tiles, 3 = service (x + FC)
  const int l   = tid & 63;
  const int c   = l & 15;          // batch col (B/C/D) and M-row (A)
  const int q   = l >> 4;          // lane quad
  const size_t bb = (size_t)blockIdx.x * NB;
  const bool isSvc = (wid == 3);

  // ---- loop-invariant A fragments ----
  F8 aR0, aR1, aZ0, aZ1, aG0, aG1, aGI;   // gate waves
  F8 aFC0, aFC1;                          // service wave
  if (!isSvc) {
    const int rrow = wid * 16 + c;
    const int zrow = 48 + wid * 16 + c;
    const int nrow = 96 + wid * 16 + c;
    const float* wr = W_hh + rrow * H; const float* ir  = W_ih + rrow * DM;
    const float* wz = W_hh + zrow * H; const float* iz  = W_ih + zrow * DM;
    const float* wn = W_hh + nrow * H; const float* in_ = W_ih + nrow * DM;
    const float bs = b_ih[rrow] + b_hh[rrow];
    const float bz = b_ih[zrow] + b_hh[zrow];
    const float bh = b_hh[nrow], bi = b_ih[nrow];
#pragma unroll
    for (int w = 0; w < 4; ++w) {
      const int k0 = 8 * q + 2 * w;
      aR0.u[w] = pk(SRZ * wr[k0], SRZ * wr[k0 + 1]);
      aZ0.u[w] = pk(SRZ * wz[k0], SRZ * wz[k0 + 1]);
      aG0.u[w] = pk(SN * wn[k0], SN * wn[k0 + 1]);
      aR1.u[w] = pk(SRZ * kv48(wr, ir, bs, 32 + k0), SRZ * kv48(wr, ir, bs, 33 + k0));
      aZ1.u[w] = pk(SRZ * kv48(wz, iz, bz, 32 + k0), SRZ * kv48(wz, iz, bz, 33 + k0));
      aG1.u[w] = pk(SN * kv48(wn, nullptr, bh, 32 + k0), SN * kv48(wn, nullptr, bh, 33 + k0));
      // gi for n-gate rides B1: A-slots at chunk-1 k 48..54 (q==2 lanes).
      // k48-53 = SN*W_ih, k54 = SN*b_ih (vs B1's 1.0), k55 = 0 (vs 0).
      const int kc = 32 + k0;   // chunk-1 k of this pair's low element
      auto gv = [&](int k) -> float {
        if (k >= 48 && k < 54) return SN * in_[k - 48];
        if (k == 54) return SN * bi;
        return 0.0f;
      };
      aGI.u[w] = (q == 2) ? pk(gv(kc), gv(kc + 1)) : 0u;
    }
  } else {
    const bool vr = (c < DM);
    const float* wr = vr ? (fc_w + c * H) : nullptr;
    const float fb = vr ? fc_b[c] : 0.0f;
#pragma unroll
    for (int w = 0; w < 4; ++w) {
      const int k0 = 8 * q + 2 * w;
      aFC0.u[w] = wr ? pk(wr[k0], wr[k0 + 1]) : 0u;
      aFC1.u[w] = pk(kv48(wr, nullptr, fb, 32 + k0), kv48(wr, nullptr, fb, 33 + k0));
    }
  }

  // ---- LDS init: zero everything, BARRIER, then payload stores ----
  for (int i = tid; i < 2 * 16 * CSTR; i += 256) ((unsigned*)hbuf)[i] = 0u;
  __syncthreads();

  if (tid < 32) hbuf[tid >> 4][(tid & 15) * CSTR + 27] = 0x00003C00u;  // (1.0, 0)

  // service wave x-pipeline: lane ll<48 owns col=ll/3, dword dw=ll%3
  const int ll = (l < 48) ? l : 47;
  const int xcol = ll / 3, xdw = ll - 3 * xcol;
  const float* xptr = x + (bb + xcol) * (size_t)(T * DM) + 2 * xdw;
  const int xwr = xcol * CSTR + 24 + xdw;
  float2 nxt = {0.0f, 0.0f};
  if (isSvc) {
    const float2 v0 = *(const float2*)xptr;                  // x[0]
    if (l < 48) hbuf[0][xwr] = pk(v0.x, v0.y);
    nxt = *(const float2*)(xptr + DM);                       // x[1]
  }

  float* yp = y + (bb + c) * (size_t)(T * DM);
  const f32x4 z4 = {0.0f, 0.0f, 0.0f, 0.0f};
  float hf[4] = {0.0f, 0.0f, 0.0f, 0.0f};  // rows 16wid+4q+j, col c

  const int rd0 = c * CSTR + 4 * q;        // B0: pairs 4q..4q+3  (k 8q..8q+7)
  const int rd1 = c * CSTR + 16 + 4 * q;   // B1: h32-47 | x | (1,0) | zeros
  const int wr_ = c * CSTR + 8 * wid + 2 * q;

  __syncthreads();

  auto STEP = [&](const unsigned* hb, unsigned* hn, int s) {
    if (!isSvc) {
      F8 B0, B1;
      const uint4 h0 = *(const uint4*)&hb[rd0];
      const uint4 h1 = *(const uint4*)&hb[rd1];
      B0.u[0] = h0.x; B0.u[1] = h0.y; B0.u[2] = h0.z; B0.u[3] = h0.w;
      B1.u[0] = h1.x; B1.u[1] = h1.y; B1.u[2] = h1.z; B1.u[3] = h1.w;

      f32x4 aR = __builtin_amdgcn_mfma_f32_16x16x32_f16(aR0.v, B0.v, z4, 0, 0, 0);
      aR = __builtin_amdgcn_mfma_f32_16x16x32_f16(aR1.v, B1.v, aR, 0, 0, 0);
      f32x4 aZ = __builtin_amdgcn_mfma_f32_16x16x32_f16(aZ0.v, B0.v, z4, 0, 0, 0);
      aZ = __builtin_amdgcn_mfma_f32_16x16x32_f16(aZ1.v, B1.v, aZ, 0, 0, 0);
      f32x4 aG = __builtin_amdgcn_mfma_f32_16x16x32_f16(aG0.v, B0.v, z4, 0, 0, 0);
      aG = __builtin_amdgcn_mfma_f32_16x16x32_f16(aG1.v, B1.v, aG, 0, 0, 0);
      f32x4 aI = __builtin_amdgcn_mfma_f32_16x16x32_f16(aGI.v, B1.v, z4, 0, 0, 0);

      // exponentials first (fills the TRANS pipe), then merged r/z rcp
      float er[4], ez[4];
#pragma unroll
      for (int j = 0; j < 4; ++j) { er[j] = fexp2(aR[j]); ez[j] = fexp2(aZ[j]); }

#pragma unroll
      for (int j = 0; j < 4; ++j) {
        const float pa = 1.0f + er[j], pb = 1.0f + ez[j];
        const float pi_ = frcp(pa * pb);
        const float r_ = pi_ * pb;             // sigmoid(pre_r)
        const float z_ = pi_ * pa;             // sigmoid(pre_z)
        const float u_ = frcp(fexp2(fmaf(r_, aG[j], aI[j])) + 1.0f);
        const float n_ = fmaf(-2.0f, u_, 1.0f);              // tanh
        hf[j] = fmaf(z_, hf[j] - n_, n_);                    // n + z*(h-n)
        if (j == 1) hn[wr_] = pk_rtn(hf[0], hf[1]);          // early half-write
      }
      hn[wr_ + 1] = pk_rtn(hf[2], hf[3]);
    } else {
      // FC: y[s-1] from h[s-1] (this read buffer)
      F8 B0, B1;
      const uint4 h0 = *(const uint4*)&hb[rd0];
      const uint4 h1 = *(const uint4*)&hb[rd1];
      B0.u[0] = h0.x; B0.u[1] = h0.y; B0.u[2] = h0.z; B0.u[3] = h0.w;
      B1.u[0] = h1.x; B1.u[1] = h1.y; B1.u[2] = h1.z; B1.u[3] = h1.w;
      f32x4 ya = __builtin_amdgcn_mfma_f32_16x16x32_f16(aFC0.v, B0.v, z4, 0, 0, 0);
      ya = __builtin_amdgcn_mfma_f32_16x16x32_f16(aFC1.v, B1.v, ya, 0, 0, 0);
      if (s > 0) {
        if (q == 0) {
          float2 s0 = {ya[0], ya[1]}, s1 = {ya[2], ya[3]};
          *(float2*)(yp + (s - 1) * DM) = s0;
          *(float2*)(yp + (s - 1) * DM + 2) = s1;
        } else if (q == 1) {
          float2 sv = {ya[0], ya[1]};
          *(float2*)(yp + (s - 1) * DM + 4) = sv;
        }
      }
      // commit x[s+1] into the write buffer (read next step), issue x[s+2]
      if (l < 48) hn[xwr] = pk(nxt.x, nxt.y);
      const int tn = (s + 2 < T) ? (s + 2) : (T - 1);
      nxt = *(const float2*)(xptr + tn * DM);
    }
    bar_lgkm();
  };

#pragma unroll 1
  for (int s2 = 0; s2 < T; s2 += 2) {
    STEP(&hbuf[0][0], &hbuf[1][0], s2);
    STEP(&hbuf[1][0], &hbuf[0][0], s2 + 1);
  }

  // epilogue: y[T-1] from h[T-1] (in hbuf[0]; last barrier already passed)
  if (isSvc) {
    const unsigned* hb = &hbuf[0][0];
    F8 B0, B1;
    const uint4 h0 = *(const uint4*)&hb[rd0];
    const uint4 h1 = *(const uint4*)&hb[rd1];
    B0.u[0] = h0.x; B0.u[1] = h0.y; B0.u[2] = h0.z; B0.u[3] = h0.w;
    B1.u[0] = h1.x; B1.u[1] = h1.y; B1.u[2] = h1.z; B1.u[3] = h1.w;
    f32x4 ya = __builtin_amdgcn_mfma_f32_16x16x32_f16(aFC0.v, B0.v, z4, 0, 0, 0);
    ya = __builtin_amdgcn_mfma_f32_16x16x32_f16(aFC1.v, B1.v, ya, 0, 0, 0);
    if (q == 0) {
      float2 s0 = {ya[0], ya[1]}, s1 = {ya[2], ya[3]};
      *(float2*)(yp + (T - 1) * DM) = s0;
      *(float2*)(yp + (T - 1) * DM + 2) = s1;
    } else if (q == 1) {
      float2 sv = {ya[0], ya[1]};
      *(float2*)(yp + (T - 1) * DM + 4) = sv;
    }
  }
}

}  // namespace

extern "C" void kernel_launch(void* const* d_in, const int* in_sizes, int n_in,
                              void* d_out, int out_size, void* d_ws, size_t ws_size,
                              hipStream_t stream) {
  const float* x    = (const float*)d_in[0];
  const float* W_ih = (const float*)d_in[1];
  const float* W_hh = (const float*)d_in[2];
  const float* b_ih = (const float*)d_in[3];
  const float* b_hh = (const float*)d_in[4];
  const float* fc_w = (const float*)d_in[5];
  const float* fc_b = (const float*)d_in[6];
  float* y = (float*)d_out;

  constexpr int B = 2048;
  gru_mfma5<<<B / NB, 256, 0, stream>>>(x, W_ih, W_hh, b_ih, b_hh, fc_w, fc_b, y);
}